// Round 1
// baseline (2593.855 us; speedup 1.0000x reference)
//
#include <hip/hip_runtime.h>
#include <math.h>

#define BN 2048
#define DN 8
#define NEGW -1e9f

static __device__ __forceinline__ float wave_reduce_max(float v){
  #pragma unroll
  for (int off = 32; off > 0; off >>= 1) v = fmaxf(v, __shfl_xor(v, off, 64));
  return v;
}
static __device__ __forceinline__ float wave_reduce_sum(float v){
  #pragma unroll
  for (int off = 32; off > 0; off >>= 1) v += __shfl_xor(v, off, 64);
  return v;
}

// Transpose inputs into per-dim columns, build masked y, counts, logw.
__global__ void setup_kernel(const float* __restrict__ pred, const float* __restrict__ targ,
                             float* __restrict__ xcol, float* __restrict__ ycol,
                             float* __restrict__ logw, float* __restrict__ counts){
  int d = blockIdx.x;          // 8 blocks
  int t = threadIdx.x;         // 256 threads
  int lane = t & 63, wave = t >> 6;
  float mk[BN/256];
  float c = 0.f;
  for (int k = 0; k < BN/256; k++){
    int i = t + k*256;
    float tv = targ[i*DN + d];
    bool m = !(tv != tv);      // !isnan
    mk[k] = m ? 1.f : 0.f;
    c += mk[k];
    ycol[d*BN + i] = m ? tv : 0.f;
    xcol[d*BN + i] = pred[i*DN + d];
  }
  __shared__ float sh[4];
  __shared__ float logn_sh;
  float cw = wave_reduce_sum(c);
  if (lane == 0) sh[wave] = cw;
  __syncthreads();
  if (t == 0){
    float tot = sh[0] + sh[1] + sh[2] + sh[3];
    counts[d] = tot;
    logn_sh = logf(fmaxf(tot, 1.f));
  }
  __syncthreads();
  float ln = logn_sh;
  for (int k = 0; k < BN/256; k++){
    int i = t + k*256;
    logw[d*BN + i] = (mk[k] > 0.f) ? -ln : NEGW;
  }
}

// One Sinkhorn phase: 4 softmins (f,g,a,b) for all 8 dims.
// mode 0 = init (h = logw, no damping)
// mode 1 = scan step (h = logw + dual/eps, damped 0.5*(old+new))
// mode 2 = final extrapolation (f,g full update; a,b damped)
//
// Row-constant shift trick: h[j] - (x_i - y_j)^2/(2 eps)
//   = (h[j] - y_j^2/(2 eps)) + (x_i/eps) * y_j - x_i^2/(2 eps)
// Everything is kept in log2 domain so exp2f/log2f map to v_exp_f32/v_log_f32.
__global__ __launch_bounds__(256) void sink_step(
      const float* __restrict__ xcol, const float* __restrict__ ycol,
      const float* __restrict__ logw,
      const float* __restrict__ dold, float* __restrict__ dnew,
      float eps, float inv_eps, int mode){
  const float L2E = 1.44269504088896340736f;
  const float LN2 = 0.69314718055994530942f;
  int bid   = blockIdx.x;
  int chunk = bid & 31;        // 32 row-chunks of 64 rows
  int mat   = (bid >> 5) & 3;  // 0:f 1:g 2:a 3:b
  int d     = bid >> 7;        // dim
  int lane  = threadIdx.x & 63;
  int wave  = threadIdx.x >> 6;

  const float* xb = xcol + d*BN;
  const float* yb = ycol + d*BN;
  const float* lw = logw + d*BN;
  const float* ri; const float* pj; int hsel;
  switch (mat){
    case 0:  ri = xb; pj = yb; hsel = 1; break;  // ft: rows x, pts y, dual g
    case 1:  ri = yb; pj = xb; hsel = 0; break;  // gt: rows y, pts x, dual f
    case 2:  ri = xb; pj = xb; hsel = 2; break;  // at
    default: ri = yb; pj = yb; hsel = 3; break;  // bt
  }
  const float* hd  = dold + (size_t)hsel*DN*BN + d*BN;
  const float* dmp = dold + (size_t)mat *DN*BN + d*BN;
  float*       op  = dnew + (size_t)mat *DN*BN + d*BN;

  const float c1 = L2E * inv_eps;          // log2-domain 1/eps
  const float c2 = 0.5f * inv_eps * L2E;   // log2-domain 1/(2 eps)

  // Cache this lane's j-slice (32 of 2048) in registers.
  float yv[32], h2[32];
  #pragma unroll
  for (int k = 0; k < 32; k++){
    int j = lane + (k << 6);
    float y  = pj[j];
    float hv = lw[j];
    if (mode != 0) hv = fmaf(hd[j], inv_eps, hv);
    yv[k] = y;
    h2[k] = fmaf(-c2 * y, y, L2E * hv);
  }

  int row0 = chunk*64 + wave*16;
  float res = 0.f;
  #pragma unroll 1
  for (int r = 0; r < 16; r++){
    int i = row0 + r;
    float xi    = ri[i];                 // wave-uniform broadcast load
    float alpha = c1 * xi;
    float beta2 = c2 * xi * xi;
    float m = -INFINITY;
    #pragma unroll
    for (int k = 0; k < 32; k++) m = fmaxf(m, fmaf(alpha, yv[k], h2[k]));
    m = wave_reduce_max(m);
    float s = 0.f;
    #pragma unroll
    for (int k = 0; k < 32; k++) s += exp2f(fmaf(alpha, yv[k], h2[k]) - m);
    s = wave_reduce_sum(s);
    float lse2 = (m + log2f(s)) - beta2;     // log2-domain LSE (shift restored)
    float tn = -eps * (LN2 * lse2);
    float outv;
    if (mode == 1 || (mode == 2 && mat >= 2)) outv = 0.5f * (dmp[i] + tn);
    else                                      outv = tn;
    if (lane == r) res = outv;
  }
  if (lane < 16) op[row0 + lane] = res;
}

__global__ void reduce_kernel(const float* __restrict__ dual, const float* __restrict__ logw,
                              const float* __restrict__ counts, float* __restrict__ out){
  int d = blockIdx.x;
  int t = threadIdx.x;
  int lane = t & 63, wave = t >> 6;
  float acc = 0.f;
  for (int k = 0; k < BN/256; k++){
    int i = t + k*256;
    float w  = expf(logw[d*BN + i]);   // exp(-1e9) -> 0, else 1/n
    float fv = dual[0*DN*BN + d*BN + i];
    float gv = dual[1*DN*BN + d*BN + i];
    float av = dual[2*DN*BN + d*BN + i];
    float bv = dual[3*DN*BN + d*BN + i];
    acc += w * ((fv - av) + (gv - bv));
  }
  __shared__ float sh[4];
  float aw = wave_reduce_sum(acc);
  if (lane == 0) sh[wave] = aw;
  __syncthreads();
  if (t == 0){
    float tot = sh[0] + sh[1] + sh[2] + sh[3];
    out[1 + d] = (counts[d] > 1.5f) ? tot : 0.f;
  }
}

__global__ void total_kernel(float* __restrict__ out){
  if (threadIdx.x == 0 && blockIdx.x == 0){
    float s = 0.f;
    for (int d = 0; d < DN; d++) s += out[1 + d];
    out[0] = s / (float)DN;
  }
}

extern "C" void kernel_launch(void* const* d_in, const int* in_sizes, int n_in,
                              void* d_out, int out_size, void* d_ws, size_t ws_size,
                              hipStream_t stream){
  const float* pred = (const float*)d_in[0];
  const float* targ = (const float*)d_in[1];
  float* out = (float*)d_out;
  float* ws  = (float*)d_ws;

  float* xcol   = ws;
  float* ycol   = ws + (size_t)DN*BN;
  float* logw   = ws + (size_t)2*DN*BN;
  float* counts = ws + (size_t)3*DN*BN;
  float* buf0   = ws + (size_t)3*DN*BN + 64;
  float* buf1   = buf0 + (size_t)4*DN*BN;

  // eps schedule (matches geomloss: diameter^p -> blur^p geometric, ratio scaling^p)
  float eps_list[64]; int n = 0;
  {
    const double P = 2.0, DIAM = 8.0, BLUR = 0.05, SC = 0.9;
    double ls = P*log(DIAM), le = P*log(BLUR), st = P*log(SC);
    eps_list[n++] = (float)pow(DIAM, P);                 // 64
    int cnt = (int)ceil((le - ls)/st);                   // 49
    for (int k = 0; k < cnt; k++) eps_list[n++] = (float)exp(ls + st*(double)k);
    eps_list[n++] = (float)(BLUR*BLUR);                  // 0.0025
  }

  setup_kernel<<<DN, 256, 0, stream>>>(pred, targ, xcol, ycol, logw, counts);

  dim3 grid(DN*4*32), blk(256);
  float* cur = buf0; float* nxt = buf1;
  {
    float e = eps_list[0];
    sink_step<<<grid, blk, 0, stream>>>(xcol, ycol, logw, cur, cur, e, 1.f/e, 0);
  }
  for (int k = 0; k < n; k++){
    float e = eps_list[k];
    sink_step<<<grid, blk, 0, stream>>>(xcol, ycol, logw, cur, nxt, e, 1.f/e, 1);
    float* tmp = cur; cur = nxt; nxt = tmp;
  }
  {
    float e = eps_list[n-1];
    sink_step<<<grid, blk, 0, stream>>>(xcol, ycol, logw, cur, nxt, e, 1.f/e, 2);
    float* tmp = cur; cur = nxt; nxt = tmp;
  }
  reduce_kernel<<<DN, 256, 0, stream>>>(cur, logw, counts, out);
  total_kernel<<<1, 64, 0, stream>>>(out);
}